// Round 19
// baseline (47.907 us; speedup 1.0000x reference)
//
#include <hip/hip_runtime.h>

#define NEL 1024
#define NUP 512
#define DEMB 256
#define WID 64

#define NEMB_BLK 1024   // embed blocks at grid head
#define NPAIR_BLK 2048  // 512 pairs per block

typedef __attribute__((ext_vector_type(4))) float f32x4;
typedef __attribute__((ext_vector_type(16))) float f32x16;
typedef __attribute__((ext_vector_type(4))) unsigned int u32x4;
typedef __attribute__((ext_vector_type(8))) _Float16 f16x8;
typedef __attribute__((ext_vector_type(2))) _Float16 h2;

#define CTANH 2.8853900817779268f   // 2*log2(e) (embed path only)
#define LOG2E 1.4426950408889634f
#define LN2   0.6931471805599453f

// ws float layout:
//  [0..1023]        : 64 cache-line buckets (stride 16): pair at +0, embJ0 at +4, embJ1 at +8
//  [1024 + s*512]   : per-set tables: b1/4 [64] f32 | w2f f16[64] (frag-order, *4*scale) @+64
//                     | w0f f16[256] (/4) @+96 | b0f f16[64] (/4) @+224 | {A, log2e/F} @+256
//  [2048 ..]        : w1f: per-set 4096 f16 (frag-order, ORIGINAL scale), set stride 2048 floats

__device__ __forceinline__ float tanh_pre(float y) {   // embed path (y = CTANH*a)
    float e = __builtin_amdgcn_exp2f(y);
    return fmaf(-2.0f, __builtin_amdgcn_rcpf(e + 1.0f), 1.0f);
}

__device__ __forceinline__ float softplus_f(float x) {
    return fmaxf(x, 0.0f) + __logf(1.0f + __expf(-fabsf(x)));
}

__device__ __forceinline__ h2 h2s(float f) {
    _Float16 v = (_Float16)f; h2 r; r[0] = v; r[1] = v; return r;
}
__device__ __forceinline__ h2 bch2(unsigned u) { return __builtin_bit_cast(h2, u); }
__device__ __forceinline__ unsigned h2bits(h2 h) { return __builtin_bit_cast(unsigned, h); }

// u = x/4 (prescaled upstream). Returns tanh(x)/4 ~= uc*P(uc^2), uc=clamp(u,+-1).
// The *4 is folded into the CONSUMING layer's weights (W1 original; w2 *= 4).
__device__ __forceinline__ h2 tanh2p(h2 u) {
    u = __builtin_elementwise_min(h2s(1.0f), __builtin_elementwise_max(h2s(-1.0f), u));
    h2 v = u * u;
    h2 p = h2s(-5.150581f);
    p = __builtin_elementwise_fma(p, v, h2s(16.252870f));
    p = __builtin_elementwise_fma(p, v, h2s(-19.909140f));
    p = __builtin_elementwise_fma(p, v, h2s(12.125338f));
    p = __builtin_elementwise_fma(p, v, h2s(-4.052176f));
    p = __builtin_elementwise_fma(p, v, h2s(0.983638f));
    return u * p;
}

__global__ __launch_bounds__(256) void prep_kernel(
    const float* __restrict__ W0s, const float* __restrict__ b0s,
    const float* __restrict__ W1s, const float* __restrict__ b1s, const float* __restrict__ W2s,
    const float* __restrict__ W0d, const float* __restrict__ b0d,
    const float* __restrict__ W1d, const float* __restrict__ b1d, const float* __restrict__ W2d,
    const float* __restrict__ As, const float* __restrict__ Ad,
    const float* __restrict__ ss, const float* __restrict__ sd,
    float* __restrict__ wsf)
{
    const int b = blockIdx.x, tid = threadIdx.x;
    if (b < 16) {
        // W1 -> f16 fragment-order (ORIGINAL scale): per block (s, h, kc): 512 f16
        const int s = b >> 3, h = (b >> 2) & 1, kc = b & 3;
        const float* W1 = s ? W1d : W1s;
        _Float16* w1out = (_Float16*)(wsf + 2048) + s * 4096 + (h * 4 + kc) * 512;
        #pragma unroll
        for (int it = 0; it < 2; ++it) {
            const int id = tid + it * 256;       // id = l*8 + e
            const int l = id >> 3, e = id & 7;
            const int k = kc * 16 + (l >> 5) * 8 + e;
            const int n = h * 32 + (l & 31);
            w1out[id] = (_Float16)W1[k * 64 + n];
        }
    } else {
        for (int idx = tid; idx < 1024; idx += 256) wsf[idx] = 0.0f;
        #pragma unroll
        for (int s = 0; s < 2; ++s) {
            const float* W0 = s ? W0d : W0s;
            const float* b0 = s ? b0d : b0s;
            const float* b1 = s ? b1d : b1s;
            const float* w2 = s ? W2d : W2s;
            const float scl = (s ? sd : ss)[0];
            const int base = 1024 + s * 512;
            if (tid < 64) wsf[base + tid] = 0.25f * b1[tid];            // b1/4, plain f32
            if (tid < 64) {                                             // w2f frag-order, *4*scale
                const int h = tid >> 5, hi = (tid >> 4) & 1, rp = (tid >> 1) & 7, wh = tid & 1;
                const int n = h * 32 + ((2 * rp) & 3) + 8 * (rp >> 1) + 4 * hi + wh;
                ((_Float16*)(wsf + base + 64))[tid] = (_Float16)(4.0f * scl * w2[n]);
            }
            {                                                           // w0f packed pairs, /4
                const int kc = tid >> 6, hi = (tid >> 5) & 1, ep = (tid >> 3) & 3;
                const int k = (tid >> 1) & 3, wh = tid & 1;
                const int n = kc * 16 + hi * 8 + 2 * ep + wh;
                ((_Float16*)(wsf + base + 96))[tid] = (_Float16)(0.25f * W0[k * 64 + n]);
            }
            if (tid < 64) {                                             // b0f packed pairs, /4
                const int kc = tid >> 4, hi = (tid >> 3) & 1, ep = (tid >> 1) & 3, wh = tid & 1;
                ((_Float16*)(wsf + base + 224))[tid] = (_Float16)(0.25f * b0[kc * 16 + hi * 8 + 2 * ep + wh]);
            }
            if (tid == 0) {
                const float A = softplus_f((s ? Ad : As)[0]);
                wsf[base + 256] = A;
                wsf[base + 257] = LOG2E * __builtin_amdgcn_rsqf(2.0f * A);
            }
        }
    }
}

// Blocks [0,1024): embed MLP, 1 row/block, split-k across 4 waves.
// Blocks [1024,3072): 512 pairs each; wave = FOUR 32-pair tiles, each followed
//   by sched_barrier(0) (the only spill-free multi-tile form: allocator pins
//   VGPR=64 regardless of launch_bounds and spills interleaved schedules —
//   R15/R17 evidence; R16/R18 fenced form verified clean).
__global__ __launch_bounds__(256, 4) void pair_kernel(
    const float* __restrict__ electrons,
    const float* __restrict__ wsf,
    float* __restrict__ accum,
    const float* __restrict__ emb,
    const float* __restrict__ We0, const float* __restrict__ be0,
    const float* __restrict__ We1, const float* __restrict__ be1,
    const float* __restrict__ We2, const float* __restrict__ be2,
    const float* __restrict__ mlp_scale, const float* __restrict__ log_bias)
{
    __shared__ __align__(16) char smem[8592];
    const int tid  = threadIdx.x;
    const int bidx = blockIdx.x;
    const int lane = tid & 63, wv = tid >> 6;

    if (bidx < NEMB_BLK) {
        // ---------------- embed path (register-light; R8 structure) ----------
        float* xs    = (float*)smem;            // 256
        float* part1 = (float*)smem + 256;      // 256
        float* h0s   = (float*)smem + 512;      // 64
        float* part2 = (float*)smem + 576;      // 256
        const int r = bidx;

        xs[tid] = emb[(r << 8) + tid];
        __syncthreads();

        const int kb = wv << 6;
        float a0 = 0, a1 = 0, a2 = 0, a3 = 0;
        #pragma unroll
        for (int q = 0; q < 64; q += 4) {
            a0 = fmaf(xs[kb + q],     We0[(kb + q)     * WID + lane], a0);
            a1 = fmaf(xs[kb + q + 1], We0[(kb + q + 1) * WID + lane], a1);
            a2 = fmaf(xs[kb + q + 2], We0[(kb + q + 2) * WID + lane], a2);
            a3 = fmaf(xs[kb + q + 3], We0[(kb + q + 3) * WID + lane], a3);
        }
        part1[(wv << 6) + lane] = (a0 + a1) + (a2 + a3);
        __syncthreads();

        if (wv == 0) {
            const float s = part1[lane] + part1[64 + lane] + part1[128 + lane]
                          + part1[192 + lane] + be0[lane];
            h0s[lane] = tanh_pre(CTANH * s);
        }
        __syncthreads();

        const int kb2 = wv << 4;
        float c0 = 0, c1 = 0;
        #pragma unroll
        for (int q = 0; q < 16; q += 2) {
            c0 = fmaf(h0s[kb2 + q],     We1[(kb2 + q)     * WID + lane], c0);
            c1 = fmaf(h0s[kb2 + q + 1], We1[(kb2 + q + 1) * WID + lane], c1);
        }
        part2[(wv << 6) + lane] = c0 + c1;
        __syncthreads();

        if (wv == 0) {
            const float c = part2[lane] + part2[64 + lane] + part2[128 + lane]
                          + part2[192 + lane] + be1[lane];
            const float h1 = tanh_pre(CTANH * c);
            float p0 = h1 * We2[2 * lane], p1 = h1 * We2[2 * lane + 1];
            #pragma unroll
            for (int off = 32; off; off >>= 1) {
                p0 += __shfl_down(p0, off);
                p1 += __shfl_down(p1, off);
            }
            if (lane == 0) {
                const int b = (r & 63) << 4;
                atomicAdd(&accum[b + 4], (p0 + be2[0]) * mlp_scale[0]);
                atomicAdd(&accum[b + 8], (p1 + be2[1]) * mlp_scale[1] + log_bias[0]);
            }
        }
        return;
    }

    // ---------------- pair path ----------------
    char*  w1lds = smem;                      // 8192 B: f16 frag-order W1
    float* b1sh  = (float*)(smem + 8192);     // 64 f32 (b1/4)
    char*  w2lds = smem + 8448;               // 128 B: f16 frag-order w2*4*scale
    float* wsum  = (float*)(smem + 8576);     // 4

    const int pb = bidx - NEMB_BLK;
    const int i  = pb >> 1;
    const int jb_blk = (pb & 1) << 9;         // 512 j per block (spin-uniform)
    const int sset = ((i < NUP) == (jb_blk < NUP)) ? 0 : 1;
    const float* tb = wsf + 1024 + sset * 512;

    // stage: W1 frags (512 float4), b1/4 (16), w2f (8)
    {
        const float4* src = (const float4*)(wsf + 2048 + sset * 2048);
        float4* dst = (float4*)w1lds;
        dst[tid]       = src[tid];
        dst[tid + 256] = src[tid + 256];
        if (tid < 16) ((float4*)b1sh)[tid] = ((const float4*)tb)[tid];
        if (tid < 8)  ((float4*)w2lds)[tid] = ((const float4*)(tb + 64))[tid];
    }
    const float A     = tb[256];
    const float invF2 = tb[257];
    const char* w0g = (const char*)(tb + 96);    // f16[256], /4
    const char* b0g = (const char*)(tb + 224);   // f16[64], /4

    const int hi = lane >> 5, p32 = lane & 31;
    const int jA = jb_blk + (wv << 7) + p32;     // wave owns 128-j strip

    const float eix = electrons[3 * i], eiy = electrons[3 * i + 1], eiz = electrons[3 * i + 2];

    __syncthreads();

    float partial = 0.0f;

    // ===== FOUR fenced tiles — per-tile state dies before the fence =====
    #pragma unroll
    for (int tile = 0; tile < 4; ++tile) {
        const int j = jA + (tile << 5);
        const bool diag = (j == i);

        float dx = eix - electrons[3 * j];
        float dy = eiy - electrons[3 * j + 1];
        float dz = eiz - electrons[3 * j + 2];
        if (diag) { dx = 0.0f; dy = 0.0f; dz = 0.0f; }
        float r2 = fmaf(dx, dx, fmaf(dy, dy, dz * dz));
        if (diag) r2 = 1.0f;
        const float rr    = __builtin_amdgcn_sqrtf(r2);
        const float inv_r = __builtin_amdgcn_rcpf(rr);
        const float l1p   = __builtin_amdgcn_logf(1.0f + rr) * LN2;
        const float gf    = l1p * inv_r;
        const float cusp = (hi == 0 && !diag)
            ? A * (__builtin_amdgcn_exp2f(-rr * invF2) - 1.0f) * inv_r : 0.0f;

        const h2 fs0 = h2s(dx * gf);
        const h2 fs1 = h2s(dy * gf);
        const h2 fs2 = h2s(dz * gf);
        const h2 fs3 = h2s(diag ? 0.0f : l1p);

        // ---- layer 1: packed f16 (W0,b0 prescaled /4) into B-fragments ----
        f16x8 afr[4];
        #pragma unroll
        for (int kc = 0; kc < 4; ++kc) {
            const u32x4 b0v = *(const u32x4*)(b0g + (((kc << 1) + hi) << 4));
            u32x4 frag;
            #pragma unroll
            for (int ep = 0; ep < 4; ++ep) {
                const u32x4 wv4 = *(const u32x4*)(w0g + (((kc << 1) + hi) << 6) + (ep << 4));
                h2 a = bch2(b0v[ep]);
                a = __builtin_elementwise_fma(bch2(wv4[0]), fs0, a);
                a = __builtin_elementwise_fma(bch2(wv4[1]), fs1, a);
                a = __builtin_elementwise_fma(bch2(wv4[2]), fs2, a);
                a = __builtin_elementwise_fma(bch2(wv4[3]), fs3, a);
                frag[ep] = h2bits(tanh2p(a));    // = h0/4; *4 folded into w2
            }
            afr[kc] = __builtin_bit_cast(f16x8, frag);
        }

        // ---- layer 2 (f16 MFMA, acc preloaded with b1/4) + layer 3 ----
        float ssum = 0.0f;
        #pragma unroll
        for (int h = 0; h < 2; ++h) {
            f32x16 acc;
            #pragma unroll
            for (int q = 0; q < 4; ++q) {
                const f32x4 bv = *(const f32x4*)(b1sh + (h << 5) + (q << 3) + (hi << 2));
                #pragma unroll
                for (int e = 0; e < 4; ++e) acc[(q << 2) + e] = bv[e];
            }
            #pragma unroll
            for (int kc = 0; kc < 4; ++kc) {
                const f16x8 wa = *(const f16x8*)(w1lds + ((((h << 2) + kc) << 6) + lane) * 16);
                acc = __builtin_amdgcn_mfma_f32_32x32x16_f16(wa, afr[kc], acc, 0, 0, 0);
            }
            const char* w2c = w2lds + (((h << 1) + hi) << 5);
            const u32x4 w2a = *(const u32x4*)(w2c);
            const u32x4 w2b = *(const u32x4*)(w2c + 16);
            h2 s2 = h2s(0.0f);
            #pragma unroll
            for (int q = 0; q < 4; ++q) {
                const h2 t0 = tanh2p(__builtin_bit_cast(h2,
                    __builtin_amdgcn_cvt_pkrtz(acc[(q << 2) + 0], acc[(q << 2) + 1])));
                const h2 t1 = tanh2p(__builtin_bit_cast(h2,
                    __builtin_amdgcn_cvt_pkrtz(acc[(q << 2) + 2], acc[(q << 2) + 3])));
                const unsigned wlo = (q < 2) ? w2a[(q << 1)]     : w2b[((q - 2) << 1)];
                const unsigned whi = (q < 2) ? w2a[(q << 1) + 1] : w2b[((q - 2) << 1) + 1];
                s2 = __builtin_elementwise_fma(t0, bch2(wlo), s2);
                s2 = __builtin_elementwise_fma(t1, bch2(whi), s2);
            }
            ssum += (float)s2[0] + (float)s2[1];
        }
        if (diag) ssum = 0.0f;
        partial += ssum + cusp;

        // fence: no instruction motion across tiles (keeps liveness ~1 tile)
        __builtin_amdgcn_sched_barrier(0);
    }

    #pragma unroll
    for (int off = 32; off; off >>= 1) partial += __shfl_down(partial, off);
    if (lane == 0) wsum[wv] = partial;
    __syncthreads();
    if (tid == 0)
        atomicAdd(&accum[(bidx & 63) << 4], wsum[0] + wsum[1] + wsum[2] + wsum[3]);
}

__global__ __launch_bounds__(64) void final_kernel(const float* __restrict__ accum,
                                                   float* __restrict__ out)
{
    const int lane = threadIdx.x;
    float v  = accum[(lane << 4)];
    float j0 = accum[(lane << 4) + 4];
    float j1 = accum[(lane << 4) + 8];
    #pragma unroll
    for (int off = 32; off; off >>= 1) {
        v  += __shfl_down(v, off);
        j0 += __shfl_down(j0, off);
        j1 += __shfl_down(j1, off);
    }
    if (lane == 0) {
        const float sign = (j1 > 0.0f) ? 1.0f : ((j1 < 0.0f) ? -1.0f : 0.0f);
        out[0] = sign;
        out[1] = v + j0 + logf(fabsf(j1));
    }
}

extern "C" void kernel_launch(void* const* d_in, const int* in_sizes, int n_in,
                              void* d_out, int out_size, void* d_ws, size_t ws_size,
                              hipStream_t stream) {
    const float* electrons  = (const float*)d_in[0];
    const float* embeddings = (const float*)d_in[1];
    const float* A_same     = (const float*)d_in[2];
    const float* A_diff     = (const float*)d_in[3];
    const float* Ws0_same   = (const float*)d_in[4];
    const float* bs0_same   = (const float*)d_in[5];
    const float* Ws1_same   = (const float*)d_in[6];
    const float* bs1_same   = (const float*)d_in[7];
    const float* Ws2_same   = (const float*)d_in[8];
    const float* Ws0_diff   = (const float*)d_in[9];
    const float* bs0_diff   = (const float*)d_in[10];
    const float* Ws1_diff   = (const float*)d_in[11];
    const float* bs1_diff   = (const float*)d_in[12];
    const float* Ws2_diff   = (const float*)d_in[13];
    const float* scale_same = (const float*)d_in[14];
    const float* scale_diff = (const float*)d_in[15];
    const float* We0        = (const float*)d_in[16];
    const float* be0        = (const float*)d_in[17];
    const float* We1        = (const float*)d_in[18];
    const float* be1        = (const float*)d_in[19];
    const float* We2        = (const float*)d_in[20];
    const float* be2        = (const float*)d_in[21];
    const float* mlp_scale  = (const float*)d_in[22];
    const float* log_bias   = (const float*)d_in[23];

    float* out = (float*)d_out;
    float* wsf = (float*)d_ws;

    hipLaunchKernelGGL(prep_kernel, dim3(17), dim3(256), 0, stream,
        Ws0_same, bs0_same, Ws1_same, bs1_same, Ws2_same,
        Ws0_diff, bs0_diff, Ws1_diff, bs1_diff, Ws2_diff,
        A_same, A_diff, scale_same, scale_diff, wsf);

    hipLaunchKernelGGL(pair_kernel, dim3(NEMB_BLK + NPAIR_BLK), dim3(256), 0, stream,
        electrons, wsf, wsf,
        embeddings, We0, be0, We1, be1, We2, be2, mlp_scale, log_bias);

    hipLaunchKernelGGL(final_kernel, dim3(1), dim3(64), 0, stream, wsf, out);
}

// Round 20
// 46.336 us; speedup vs baseline: 1.0339x; 1.0339x over previous
//
#include <hip/hip_runtime.h>

#define NEL 1024
#define NUP 512
#define DEMB 256
#define WID 64

#define NEMB_BLK 1024   // embed blocks at grid head
#define NPAIR_BLK 4096

typedef __attribute__((ext_vector_type(4))) float f32x4;
typedef __attribute__((ext_vector_type(16))) float f32x16;
typedef __attribute__((ext_vector_type(4))) unsigned int u32x4;
typedef __attribute__((ext_vector_type(8))) _Float16 f16x8;
typedef __attribute__((ext_vector_type(2))) _Float16 h2;

#define CTANH 2.8853900817779268f   // 2*log2(e) (embed path only)
#define LOG2E 1.4426950408889634f
#define LN2   0.6931471805599453f

// ws float layout:
//  [0..1023]        : 64 cache-line buckets (stride 16): pair at +0, embJ0 at +4, embJ1 at +8
//  [1024 + s*512]   : per-set tables: b1/4 [64] f32 | w2f f16[64] (frag-order, *4*scale) @+64
//                     | w0f f16[256] (/4) @+96 | b0f f16[64] (/4) @+224 | {A, log2e/F} @+256
//  [2048 ..]        : w1f: per-set 4096 f16 (frag-order, ORIGINAL scale), set stride 2048 floats

__device__ __forceinline__ float tanh_pre(float y) {   // embed path (y = CTANH*a)
    float e = __builtin_amdgcn_exp2f(y);
    return fmaf(-2.0f, __builtin_amdgcn_rcpf(e + 1.0f), 1.0f);
}

__device__ __forceinline__ float softplus_f(float x) {
    return fmaxf(x, 0.0f) + __logf(1.0f + __expf(-fabsf(x)));
}

__device__ __forceinline__ h2 h2s(float f) {
    _Float16 v = (_Float16)f; h2 r; r[0] = v; r[1] = v; return r;
}
__device__ __forceinline__ h2 bch2(unsigned u) { return __builtin_bit_cast(h2, u); }
__device__ __forceinline__ unsigned h2bits(h2 h) { return __builtin_bit_cast(unsigned, h); }

// u = x/4 (prescaled upstream). Returns tanh(x)/4 ~= uc*P(uc^2), uc=clamp(u,+-1).
// The *4 is folded into the CONSUMING layer's weights (W1 original; w2 *= 4).
__device__ __forceinline__ h2 tanh2p(h2 u) {
    u = __builtin_elementwise_min(h2s(1.0f), __builtin_elementwise_max(h2s(-1.0f), u));
    h2 v = u * u;
    h2 p = h2s(-5.150581f);
    p = __builtin_elementwise_fma(p, v, h2s(16.252870f));
    p = __builtin_elementwise_fma(p, v, h2s(-19.909140f));
    p = __builtin_elementwise_fma(p, v, h2s(12.125338f));
    p = __builtin_elementwise_fma(p, v, h2s(-4.052176f));
    p = __builtin_elementwise_fma(p, v, h2s(0.983638f));
    return u * p;
}

__global__ __launch_bounds__(256) void prep_kernel(
    const float* __restrict__ W0s, const float* __restrict__ b0s,
    const float* __restrict__ W1s, const float* __restrict__ b1s, const float* __restrict__ W2s,
    const float* __restrict__ W0d, const float* __restrict__ b0d,
    const float* __restrict__ W1d, const float* __restrict__ b1d, const float* __restrict__ W2d,
    const float* __restrict__ As, const float* __restrict__ Ad,
    const float* __restrict__ ss, const float* __restrict__ sd,
    float* __restrict__ wsf)
{
    const int b = blockIdx.x, tid = threadIdx.x;
    if (b < 16) {
        // W1 -> f16 fragment-order (ORIGINAL scale): per block (s, h, kc): 512 f16
        const int s = b >> 3, h = (b >> 2) & 1, kc = b & 3;
        const float* W1 = s ? W1d : W1s;
        _Float16* w1out = (_Float16*)(wsf + 2048) + s * 4096 + (h * 4 + kc) * 512;
        #pragma unroll
        for (int it = 0; it < 2; ++it) {
            const int id = tid + it * 256;       // id = l*8 + e
            const int l = id >> 3, e = id & 7;
            const int k = kc * 16 + (l >> 5) * 8 + e;
            const int n = h * 32 + (l & 31);
            w1out[id] = (_Float16)W1[k * 64 + n];
        }
    } else {
        for (int idx = tid; idx < 1024; idx += 256) wsf[idx] = 0.0f;
        #pragma unroll
        for (int s = 0; s < 2; ++s) {
            const float* W0 = s ? W0d : W0s;
            const float* b0 = s ? b0d : b0s;
            const float* b1 = s ? b1d : b1s;
            const float* w2 = s ? W2d : W2s;
            const float scl = (s ? sd : ss)[0];
            const int base = 1024 + s * 512;
            if (tid < 64) wsf[base + tid] = 0.25f * b1[tid];            // b1/4, plain f32
            if (tid < 64) {                                             // w2f frag-order, *4*scale
                const int h = tid >> 5, hi = (tid >> 4) & 1, rp = (tid >> 1) & 7, wh = tid & 1;
                const int n = h * 32 + ((2 * rp) & 3) + 8 * (rp >> 1) + 4 * hi + wh;
                ((_Float16*)(wsf + base + 64))[tid] = (_Float16)(4.0f * scl * w2[n]);
            }
            {                                                           // w0f packed pairs, /4
                const int kc = tid >> 6, hi = (tid >> 5) & 1, ep = (tid >> 3) & 3;
                const int k = (tid >> 1) & 3, wh = tid & 1;
                const int n = kc * 16 + hi * 8 + 2 * ep + wh;
                ((_Float16*)(wsf + base + 96))[tid] = (_Float16)(0.25f * W0[k * 64 + n]);
            }
            if (tid < 64) {                                             // b0f packed pairs, /4
                const int kc = tid >> 4, hi = (tid >> 3) & 1, ep = (tid >> 1) & 3, wh = tid & 1;
                ((_Float16*)(wsf + base + 224))[tid] = (_Float16)(0.25f * b0[kc * 16 + hi * 8 + 2 * ep + wh]);
            }
            if (tid == 0) {
                const float A = softplus_f((s ? Ad : As)[0]);
                wsf[base + 256] = A;
                wsf[base + 257] = LOG2E * __builtin_amdgcn_rsqf(2.0f * A);
            }
        }
    }
}

// Blocks [0,1024): embed MLP, 1 row/block, split-k across 4 waves (runs at the
//   grid head, hidden under the pair blocks).
// Blocks [1024,5120): 256 pairs each; wave = TWO 32-pair tiles with a
//   sched_barrier(0) fence between them (R16/R18: the only spill-free 2-tile
//   form — allocator pins VGPR=64 regardless of launch_bounds and spills any
//   interleaved 2-tile schedule; R15/R17 evidence. 4 tiles regressed, R19).
__global__ __launch_bounds__(256, 4) void pair_kernel(
    const float* __restrict__ electrons,
    const float* __restrict__ wsf,
    float* __restrict__ accum,
    const float* __restrict__ emb,
    const float* __restrict__ We0, const float* __restrict__ be0,
    const float* __restrict__ We1, const float* __restrict__ be1,
    const float* __restrict__ We2, const float* __restrict__ be2,
    const float* __restrict__ mlp_scale, const float* __restrict__ log_bias)
{
    __shared__ __align__(16) char smem[8592];
    const int tid  = threadIdx.x;
    const int bidx = blockIdx.x;
    const int lane = tid & 63, wv = tid >> 6;

    if (bidx < NEMB_BLK) {
        // ---------------- embed path (register-light; R8 structure) ----------
        float* xs    = (float*)smem;            // 256
        float* part1 = (float*)smem + 256;      // 256
        float* h0s   = (float*)smem + 512;      // 64
        float* part2 = (float*)smem + 576;      // 256
        const int r = bidx;

        xs[tid] = emb[(r << 8) + tid];
        __syncthreads();

        const int kb = wv << 6;
        float a0 = 0, a1 = 0, a2 = 0, a3 = 0;
        #pragma unroll
        for (int q = 0; q < 64; q += 4) {
            a0 = fmaf(xs[kb + q],     We0[(kb + q)     * WID + lane], a0);
            a1 = fmaf(xs[kb + q + 1], We0[(kb + q + 1) * WID + lane], a1);
            a2 = fmaf(xs[kb + q + 2], We0[(kb + q + 2) * WID + lane], a2);
            a3 = fmaf(xs[kb + q + 3], We0[(kb + q + 3) * WID + lane], a3);
        }
        part1[(wv << 6) + lane] = (a0 + a1) + (a2 + a3);
        __syncthreads();

        if (wv == 0) {
            const float s = part1[lane] + part1[64 + lane] + part1[128 + lane]
                          + part1[192 + lane] + be0[lane];
            h0s[lane] = tanh_pre(CTANH * s);
        }
        __syncthreads();

        const int kb2 = wv << 4;
        float c0 = 0, c1 = 0;
        #pragma unroll
        for (int q = 0; q < 16; q += 2) {
            c0 = fmaf(h0s[kb2 + q],     We1[(kb2 + q)     * WID + lane], c0);
            c1 = fmaf(h0s[kb2 + q + 1], We1[(kb2 + q + 1) * WID + lane], c1);
        }
        part2[(wv << 6) + lane] = c0 + c1;
        __syncthreads();

        if (wv == 0) {
            const float c = part2[lane] + part2[64 + lane] + part2[128 + lane]
                          + part2[192 + lane] + be1[lane];
            const float h1 = tanh_pre(CTANH * c);
            float p0 = h1 * We2[2 * lane], p1 = h1 * We2[2 * lane + 1];
            #pragma unroll
            for (int off = 32; off; off >>= 1) {
                p0 += __shfl_down(p0, off);
                p1 += __shfl_down(p1, off);
            }
            if (lane == 0) {
                const int b = (r & 63) << 4;
                atomicAdd(&accum[b + 4], (p0 + be2[0]) * mlp_scale[0]);
                atomicAdd(&accum[b + 8], (p1 + be2[1]) * mlp_scale[1] + log_bias[0]);
            }
        }
        return;
    }

    // ---------------- pair path (byte-identical to R16) ----------------
    char*  w1lds = smem;                      // 8192 B: f16 frag-order W1
    float* b1sh  = (float*)(smem + 8192);     // 64 f32 (b1/4)
    char*  w2lds = smem + 8448;               // 128 B: f16 frag-order w2*4*scale
    float* wsum  = (float*)(smem + 8576);     // 4

    const int pb = bidx - NEMB_BLK;
    const int i  = pb >> 2;
    const int jb_blk = (pb & 3) << 8;         // 256 j per block (spin-uniform)
    const int sset = ((i < NUP) == (jb_blk < NUP)) ? 0 : 1;
    const float* tb = wsf + 1024 + sset * 512;

    // stage: W1 frags (512 float4), b1/4 (16), w2f (8)
    {
        const float4* src = (const float4*)(wsf + 2048 + sset * 2048);
        float4* dst = (float4*)w1lds;
        dst[tid]       = src[tid];
        dst[tid + 256] = src[tid + 256];
        if (tid < 16) ((float4*)b1sh)[tid] = ((const float4*)tb)[tid];
        if (tid < 8)  ((float4*)w2lds)[tid] = ((const float4*)(tb + 64))[tid];
    }
    const float A     = tb[256];
    const float invF2 = tb[257];
    const char* w0g = (const char*)(tb + 96);    // f16[256], /4
    const char* b0g = (const char*)(tb + 224);   // f16[64], /4

    const int hi = lane >> 5, p32 = lane & 31;
    const int jA = jb_blk + (wv << 6) + p32;

    const float eix = electrons[3 * i], eiy = electrons[3 * i + 1], eiz = electrons[3 * i + 2];

    __syncthreads();

    float partial = 0.0f;

    // ===== TILE A, then TILE B — sched_barrier fences cross-tile motion =====
    #pragma unroll
    for (int tile = 0; tile < 2; ++tile) {
        const int j = jA + (tile << 5);
        const bool diag = (j == i);

        float dx = eix - electrons[3 * j];
        float dy = eiy - electrons[3 * j + 1];
        float dz = eiz - electrons[3 * j + 2];
        if (diag) { dx = 0.0f; dy = 0.0f; dz = 0.0f; }
        float r2 = fmaf(dx, dx, fmaf(dy, dy, dz * dz));
        if (diag) r2 = 1.0f;
        const float rr    = __builtin_amdgcn_sqrtf(r2);
        const float inv_r = __builtin_amdgcn_rcpf(rr);
        const float l1p   = __builtin_amdgcn_logf(1.0f + rr) * LN2;
        const float gf    = l1p * inv_r;
        const float cusp = (hi == 0 && !diag)
            ? A * (__builtin_amdgcn_exp2f(-rr * invF2) - 1.0f) * inv_r : 0.0f;

        const h2 fs0 = h2s(dx * gf);
        const h2 fs1 = h2s(dy * gf);
        const h2 fs2 = h2s(dz * gf);
        const h2 fs3 = h2s(diag ? 0.0f : l1p);

        // ---- layer 1: packed f16 (W0,b0 prescaled /4) into B-fragments ----
        f16x8 afr[4];
        #pragma unroll
        for (int kc = 0; kc < 4; ++kc) {
            const u32x4 b0v = *(const u32x4*)(b0g + (((kc << 1) + hi) << 4));
            u32x4 frag;
            #pragma unroll
            for (int ep = 0; ep < 4; ++ep) {
                const u32x4 wv4 = *(const u32x4*)(w0g + (((kc << 1) + hi) << 6) + (ep << 4));
                h2 a = bch2(b0v[ep]);
                a = __builtin_elementwise_fma(bch2(wv4[0]), fs0, a);
                a = __builtin_elementwise_fma(bch2(wv4[1]), fs1, a);
                a = __builtin_elementwise_fma(bch2(wv4[2]), fs2, a);
                a = __builtin_elementwise_fma(bch2(wv4[3]), fs3, a);
                frag[ep] = h2bits(tanh2p(a));    // = h0/4; *4 folded into w2
            }
            afr[kc] = __builtin_bit_cast(f16x8, frag);
        }

        // ---- layer 2 (f16 MFMA, acc preloaded with b1/4) + layer 3 ----
        float ssum = 0.0f;
        #pragma unroll
        for (int h = 0; h < 2; ++h) {
            f32x16 acc;
            #pragma unroll
            for (int q = 0; q < 4; ++q) {
                const f32x4 bv = *(const f32x4*)(b1sh + (h << 5) + (q << 3) + (hi << 2));
                #pragma unroll
                for (int e = 0; e < 4; ++e) acc[(q << 2) + e] = bv[e];
            }
            #pragma unroll
            for (int kc = 0; kc < 4; ++kc) {
                const f16x8 wa = *(const f16x8*)(w1lds + ((((h << 2) + kc) << 6) + lane) * 16);
                acc = __builtin_amdgcn_mfma_f32_32x32x16_f16(wa, afr[kc], acc, 0, 0, 0);
            }
            const char* w2c = w2lds + (((h << 1) + hi) << 5);
            const u32x4 w2a = *(const u32x4*)(w2c);
            const u32x4 w2b = *(const u32x4*)(w2c + 16);
            h2 s2 = h2s(0.0f);
            #pragma unroll
            for (int q = 0; q < 4; ++q) {
                const h2 t0 = tanh2p(__builtin_bit_cast(h2,
                    __builtin_amdgcn_cvt_pkrtz(acc[(q << 2) + 0], acc[(q << 2) + 1])));
                const h2 t1 = tanh2p(__builtin_bit_cast(h2,
                    __builtin_amdgcn_cvt_pkrtz(acc[(q << 2) + 2], acc[(q << 2) + 3])));
                const unsigned wlo = (q < 2) ? w2a[(q << 1)]     : w2b[((q - 2) << 1)];
                const unsigned whi = (q < 2) ? w2a[(q << 1) + 1] : w2b[((q - 2) << 1) + 1];
                s2 = __builtin_elementwise_fma(t0, bch2(wlo), s2);
                s2 = __builtin_elementwise_fma(t1, bch2(whi), s2);
            }
            ssum += (float)s2[0] + (float)s2[1];
        }
        if (diag) ssum = 0.0f;
        partial += ssum + cusp;

        // fence: no instruction motion between tile A and tile B
        __builtin_amdgcn_sched_barrier(0);
    }

    #pragma unroll
    for (int off = 32; off; off >>= 1) partial += __shfl_down(partial, off);
    if (lane == 0) wsum[wv] = partial;
    __syncthreads();
    if (tid == 0)
        atomicAdd(&accum[(bidx & 63) << 4], wsum[0] + wsum[1] + wsum[2] + wsum[3]);
}

__global__ __launch_bounds__(64) void final_kernel(const float* __restrict__ accum,
                                                   float* __restrict__ out)
{
    const int lane = threadIdx.x;
    float v  = accum[(lane << 4)];
    float j0 = accum[(lane << 4) + 4];
    float j1 = accum[(lane << 4) + 8];
    #pragma unroll
    for (int off = 32; off; off >>= 1) {
        v  += __shfl_down(v, off);
        j0 += __shfl_down(j0, off);
        j1 += __shfl_down(j1, off);
    }
    if (lane == 0) {
        const float sign = (j1 > 0.0f) ? 1.0f : ((j1 < 0.0f) ? -1.0f : 0.0f);
        out[0] = sign;
        out[1] = v + j0 + logf(fabsf(j1));
    }
}

extern "C" void kernel_launch(void* const* d_in, const int* in_sizes, int n_in,
                              void* d_out, int out_size, void* d_ws, size_t ws_size,
                              hipStream_t stream) {
    const float* electrons  = (const float*)d_in[0];
    const float* embeddings = (const float*)d_in[1];
    const float* A_same     = (const float*)d_in[2];
    const float* A_diff     = (const float*)d_in[3];
    const float* Ws0_same   = (const float*)d_in[4];
    const float* bs0_same   = (const float*)d_in[5];
    const float* Ws1_same   = (const float*)d_in[6];
    const float* bs1_same   = (const float*)d_in[7];
    const float* Ws2_same   = (const float*)d_in[8];
    const float* Ws0_diff   = (const float*)d_in[9];
    const float* bs0_diff   = (const float*)d_in[10];
    const float* Ws1_diff   = (const float*)d_in[11];
    const float* bs1_diff   = (const float*)d_in[12];
    const float* Ws2_diff   = (const float*)d_in[13];
    const float* scale_same = (const float*)d_in[14];
    const float* scale_diff = (const float*)d_in[15];
    const float* We0        = (const float*)d_in[16];
    const float* be0        = (const float*)d_in[17];
    const float* We1        = (const float*)d_in[18];
    const float* be1        = (const float*)d_in[19];
    const float* We2        = (const float*)d_in[20];
    const float* be2        = (const float*)d_in[21];
    const float* mlp_scale  = (const float*)d_in[22];
    const float* log_bias   = (const float*)d_in[23];

    float* out = (float*)d_out;
    float* wsf = (float*)d_ws;

    hipLaunchKernelGGL(prep_kernel, dim3(17), dim3(256), 0, stream,
        Ws0_same, bs0_same, Ws1_same, bs1_same, Ws2_same,
        Ws0_diff, bs0_diff, Ws1_diff, bs1_diff, Ws2_diff,
        A_same, A_diff, scale_same, scale_diff, wsf);

    hipLaunchKernelGGL(pair_kernel, dim3(NEMB_BLK + NPAIR_BLK), dim3(256), 0, stream,
        electrons, wsf, wsf,
        embeddings, We0, be0, We1, be1, We2, be2, mlp_scale, log_bias);

    hipLaunchKernelGGL(final_kernel, dim3(1), dim3(64), 0, stream, wsf, out);
}